// Round 3
// baseline (417.133 us; speedup 1.0000x reference)
//
#include <hip/hip_runtime.h>
#include <stdint.h>
#include <stddef.h>

#define B_N    16384
#define NCLS_N 1000
#define C_N    1280

// workspace layout (bytes). Required ws_size >= ~52.8 MB.
#define ACC_OFF    0ULL
#define COLSUM_OFF 128ULL
#define FBT_OFF    8192ULL                         // bf16 panel [512kc][4kj][1280][8]
#define WB_OFF     41951232ULL                     // bf16 panel [40kc][4kj][1024][8] (rows >=1000 zero)
#define G_OFF      44572672ULL                     // fp32 [1280][1280]
#define H_OFF      51126272ULL                     // fp32 [1024][1024]

enum { A_NLL = 0, A_KL = 1, A_L1 = 2, A_L2SQ = 3, A_SUMSQF = 4, A_FMU2 = 5, A_GFRO = 6, A_HFRO = 7 };

typedef short s16x8 __attribute__((ext_vector_type(8)));
typedef float f32x4 __attribute__((ext_vector_type(4)));

__device__ __forceinline__ unsigned short f2bf(float f) {
    union { float f; unsigned int u; } v; v.f = f;
    unsigned int u = v.u;
    u += 0x7fffu + ((u >> 16) & 1u);   // RNE
    return (unsigned short)(u >> 16);
}

__device__ __forceinline__ float wave_red(float v) {
#pragma unroll
    for (int o = 32; o; o >>= 1) v += __shfl_down(v, o, 64);
    return v;
}

// ---------------- NLL gather ----------------
__global__ __launch_bounds__(256) void nll_kernel(const float* __restrict__ lp,
                                                  const int* __restrict__ tgt,
                                                  float* __restrict__ acc) {
    int b = blockIdx.x * 256 + threadIdx.x;
    int t = tgt[b];
    float v = lp[(size_t)b * NCLS_N + t];
    v = wave_red(v);
    __shared__ float sm[4];
    int wid = threadIdx.x >> 6, lane = threadIdx.x & 63;
    if (lane == 0) sm[wid] = v;
    __syncthreads();
    if (threadIdx.x == 0) atomicAdd(&acc[A_NLL], sm[0] + sm[1] + sm[2] + sm[3]);
}

// ---------------- weights: bf16 panel cast (padded to 1024 rows) + L1 + L2sq ----------------
// lane <-> row m: panel stores are 1KB contiguous per wave instruction.
// per-thread reads are 128B contiguous per chunk (every fetched byte consumed).
__global__ __launch_bounds__(256) void wpass_kernel(const float* __restrict__ W,
                                                    short* __restrict__ Wb,
                                                    float* __restrict__ acc) {
    int m = blockIdx.x * 256 + threadIdx.x;     // 0..1023
    bool live = (m < NCLS_N);
    const float4* Wr = (const float4*)(W + (size_t)m * C_N);
    float l1 = 0.f, l2 = 0.f;
    for (int kc = 0; kc < 40; kc++) {
#pragma unroll
        for (int kj = 0; kj < 4; kj++) {
            s16x8 pk = { 0, 0, 0, 0, 0, 0, 0, 0 };
            if (live) {
                float4 a = Wr[kc * 8 + kj * 2];
                float4 b = Wr[kc * 8 + kj * 2 + 1];
                l1 += fabsf(a.x) + fabsf(a.y) + fabsf(a.z) + fabsf(a.w)
                    + fabsf(b.x) + fabsf(b.y) + fabsf(b.z) + fabsf(b.w);
                l2 += a.x * a.x + a.y * a.y + a.z * a.z + a.w * a.w
                    + b.x * b.x + b.y * b.y + b.z * b.z + b.w * b.w;
                pk[0] = (short)f2bf(a.x); pk[1] = (short)f2bf(a.y);
                pk[2] = (short)f2bf(a.z); pk[3] = (short)f2bf(a.w);
                pk[4] = (short)f2bf(b.x); pk[5] = (short)f2bf(b.y);
                pk[6] = (short)f2bf(b.z); pk[7] = (short)f2bf(b.w);
            }
            *(s16x8*)(Wb + ((size_t)(kc * 4 + kj) * 1024 + m) * 8) = pk;
        }
    }
    l1 = wave_red(l1);
    l2 = wave_red(l2);
    __shared__ float sm[4][2];
    int wid = threadIdx.x >> 6, lane = threadIdx.x & 63;
    if (lane == 0) { sm[wid][0] = l1; sm[wid][1] = l2; }
    __syncthreads();
    if (threadIdx.x == 0) {
        atomicAdd(&acc[A_L1],   sm[0][0] + sm[1][0] + sm[2][0] + sm[3][0]);
        atomicAdd(&acc[A_L2SQ], sm[0][1] + sm[1][1] + sm[2][1] + sm[3][1]);
    }
}

// ---------------- features: bf16 panel transpose + column sums + sum of squares ----------------
// lane <-> c. Reads: 256B/wave-instr coalesced. Panel stores: 1KB/wave-instr contiguous
// (fixes round-2's 138MB-vs-42MB WRITE_SIZE amplification from 16B stores at 32KB lane stride).
__global__ __launch_bounds__(256) void fpass_kernel(const float* __restrict__ F,
                                                    short* __restrict__ Fbt,
                                                    float* __restrict__ colsum,
                                                    float* __restrict__ acc) {
    int c = blockIdx.x * 256 + threadIdx.x;     // 0..1279
    int kc0 = blockIdx.y * 4;                   // 4 chunks of 32 k per block
    float cs = 0.f, sq = 0.f;
    for (int ch = 0; ch < 4; ch++) {
        int kc = kc0 + ch;
        int kbase = kc * 32;
#pragma unroll
        for (int kj = 0; kj < 4; kj++) {
            float v[8];
#pragma unroll
            for (int e = 0; e < 8; e++) v[e] = F[(size_t)(kbase + kj * 8 + e) * C_N + c];
            s16x8 pk;
#pragma unroll
            for (int e = 0; e < 8; e++) {
                cs += v[e];
                sq += v[e] * v[e];
                pk[e] = (short)f2bf(v[e]);
            }
            *(s16x8*)(Fbt + ((size_t)(kc * 4 + kj) * C_N + c) * 8) = pk;
        }
    }
    atomicAdd(&colsum[c], cs);
    sq = wave_red(sq);
    __shared__ float sm[4];
    int wid = threadIdx.x >> 6, lane = threadIdx.x & 63;
    if (lane == 0) sm[wid] = sq;
    __syncthreads();
    if (threadIdx.x == 0) atomicAdd(&acc[A_SUMSQF], sm[0] + sm[1] + sm[2] + sm[3]);
}

// ---------------- per-row: KL term + ||F mu||^2 term ----------------
// kl_row = C * (sum e^f * f)/(sum e^f) - sum f   (log s cancels analytically)
// One wave per row; one atomicAdd per block per quantity.
__global__ __launch_bounds__(256) void klpass_kernel(const float* __restrict__ F,
                                                     const float* __restrict__ colsum,
                                                     float* __restrict__ acc) {
    int wid = threadIdx.x >> 6, lane = threadIdx.x & 63;
    int gwave = blockIdx.x * 4 + wid;            // 0..4095
    const float4* M = (const float4*)colsum;

    float kl_acc = 0.f, fmu_acc = 0.f;
    for (int b = gwave; b < B_N; b += 4096) {
        const float4* Fr = (const float4*)(F + (size_t)b * C_N);
        float s = 0.f, tt = 0.f, sf = 0.f, dp = 0.f;
#pragma unroll
        for (int i = 0; i < 5; i++) {
            float4 f = Fr[lane + 64 * i];
            float4 m = M[lane + 64 * i];
            float e0 = __expf(f.x), e1 = __expf(f.y), e2 = __expf(f.z), e3 = __expf(f.w);
            s  += e0 + e1 + e2 + e3;
            tt += e0 * f.x + e1 * f.y + e2 * f.z + e3 * f.w;
            sf += f.x + f.y + f.z + f.w;
            dp += f.x * m.x + f.y * m.y + f.z * m.z + f.w * m.w;
        }
        s = wave_red(s); tt = wave_red(tt); sf = wave_red(sf); dp = wave_red(dp);
        if (lane == 0) {
            kl_acc += (float)C_N * (tt / s) - sf;
            float dot = dp * (1.f / (float)B_N);  // (F mu)_b, mu = colsum/B
            fmu_acc += dot * dot;
        }
    }
    __shared__ float sm[4][2];
    if (lane == 0) { sm[wid][0] = kl_acc; sm[wid][1] = fmu_acc; }
    __syncthreads();
    if (threadIdx.x == 0) {
        atomicAdd(&acc[A_KL],   sm[0][0] + sm[1][0] + sm[2][0] + sm[3][0]);
        atomicAdd(&acc[A_FMU2], sm[0][1] + sm[1][1] + sm[2][1] + sm[3][1]);
    }
}

// ---------------- bf16 Gram: S += X X^T over triangular tiles, K-split, atomic epilogue ----------------
// X: panel layout [kc][kj][Mp][8] bf16 (k = kc*32 + kj*8 + e).
// 128x128 tile per block, 4 waves (2x2 of 64x64), BK=32, 16x16x32 MFMA.
// Staging: lane g -> LDS At[g*16B] == At[row=g>>2][kj=g&3] row-major [128][32]; global source
// ((kc*4+kj)*Mp + i0+row)*16B -> 4 contiguous 16B streams per wave (full cache lines).
__global__ __launch_bounds__(256) void gram_kernel(const short* __restrict__ X,
                                                   float* __restrict__ S,
                                                   int Mp, int K, int T, int ntri, int chunkK) {
    __shared__ __align__(16) short At[128 * 32];
    __shared__ __align__(16) short Bt[128 * 32];
    int tid = threadIdx.x;
    int tile = blockIdx.x % ntri;
    int kc_blk = blockIdx.x / ntri;
    int bi = 0, rem = tile;
    while (rem >= T - bi) { rem -= T - bi; bi++; }
    int bj = bi + rem;
    int i0 = bi * 128, j0 = bj * 128;
    int k0 = kc_blk * chunkK;
    bool same = (bi == bj);

    int wave = tid >> 6, lane = tid & 63;
    int wm = wave >> 1, wn = wave & 1;
    int quad = lane >> 4, l16 = lane & 15;

    f32x4 acc[4][4];
#pragma unroll
    for (int i = 0; i < 4; i++)
#pragma unroll
        for (int j = 0; j < 4; j++) acc[i][j] = { 0.f, 0.f, 0.f, 0.f };

    for (int kk = 0; kk < chunkK; kk += 32) {
        int kc = (k0 + kk) >> 5;
#pragma unroll
        for (int it = 0; it < 2; it++) {
            int g = it * 256 + tid;
            int row = g >> 2, kj = g & 3;
            const short* gp = X + ((size_t)(kc * 4 + kj) * Mp + i0 + row) * 8;
            __builtin_amdgcn_global_load_lds((const __attribute__((address_space(1))) unsigned int*)gp,
                                             (__attribute__((address_space(3))) unsigned int*)(At + g * 8),
                                             16, 0, 0);
        }
        if (!same) {
#pragma unroll
            for (int it = 0; it < 2; it++) {
                int g = it * 256 + tid;
                int row = g >> 2, kj = g & 3;
                const short* gp = X + ((size_t)(kc * 4 + kj) * Mp + j0 + row) * 8;
                __builtin_amdgcn_global_load_lds((const __attribute__((address_space(1))) unsigned int*)gp,
                                                 (__attribute__((address_space(3))) unsigned int*)(Bt + g * 8),
                                                 16, 0, 0);
            }
        }
        __syncthreads();
        const short* Bsrc = same ? At : Bt;
        s16x8 af[4], bf[4];
#pragma unroll
        for (int f = 0; f < 4; f++) {
            int mrow = wm * 64 + f * 16 + l16;
            af[f] = *(const s16x8*)(At + mrow * 32 + quad * 8);
            int nrow = wn * 64 + f * 16 + l16;
            bf[f] = *(const s16x8*)(Bsrc + nrow * 32 + quad * 8);
        }
#pragma unroll
        for (int i = 0; i < 4; i++)
#pragma unroll
            for (int j = 0; j < 4; j++)
                acc[i][j] = __builtin_amdgcn_mfma_f32_16x16x32_bf16(af[i], bf[j], acc[i][j], 0, 0, 0);
        __syncthreads();
    }

#pragma unroll
    for (int i = 0; i < 4; i++)
#pragma unroll
        for (int j = 0; j < 4; j++)
#pragma unroll
            for (int r = 0; r < 4; r++) {
                int grow = i0 + wm * 64 + i * 16 + quad * 4 + r;
                int gcol = j0 + wn * 64 + j * 16 + l16;
                atomicAdd(&S[(size_t)grow * Mp + gcol], acc[i][j][r]);
            }
}

// ---------------- Frobenius^2 over computed triangular tiles (off-diag weighted 2x) ----------------
__global__ __launch_bounds__(256) void fro_reduce_kernel(const float* __restrict__ S,
                                                         int Mp, int T, float* __restrict__ slot) {
    int tile = blockIdx.x;
    int bi = 0, rem = tile;
    while (rem >= T - bi) { rem -= T - bi; bi++; }
    int bj = bi + rem;
    size_t base = (size_t)bi * 128 * Mp + (size_t)bj * 128;
    float sum = 0.f;
    for (int l = threadIdx.x * 4; l < 128 * 128; l += 1024) {
        int row = l >> 7, col = l & 127;
        float4 v = *(const float4*)(S + base + (size_t)row * Mp + col);
        sum += v.x * v.x + v.y * v.y + v.z * v.z + v.w * v.w;
    }
    sum = wave_red(sum);
    __shared__ float sm[4];
    int wid = threadIdx.x >> 6, lane = threadIdx.x & 63;
    if (lane == 0) sm[wid] = sum;
    __syncthreads();
    if (threadIdx.x == 0) {
        float w = (bi == bj) ? 1.f : 2.f;
        atomicAdd(slot, w * (sm[0] + sm[1] + sm[2] + sm[3]));
    }
}

// ---------------- final combine ----------------
__global__ __launch_bounds__(256) void final_kernel(const float* __restrict__ acc,
                                                    const float* __restrict__ colsum,
                                                    float* __restrict__ out) {
    float s = 0.f;
    for (int c = threadIdx.x; c < C_N; c += 256) { float v = colsum[c]; s += v * v; }
    s = wave_red(s);
    __shared__ float sm[4];
    int wid = threadIdx.x >> 6, lane = threadIdx.x & 63;
    if (lane == 0) sm[wid] = s;
    __syncthreads();
    if (threadIdx.x == 0) {
        double musq_raw = (double)(sm[0] + sm[1] + sm[2] + sm[3]);   // sum colsum^2 = B^2 * ||mu||^2
        double Bd = (double)B_N;
        double nll = -((double)acc[A_NLL] / Bd);
        double kl  = (double)acc[A_KL] / Bd;
        double trG = (double)acc[A_SUMSQF];
        double musq = musq_raw / (Bd * Bd);
        double cov = (double)acc[A_GFRO] / (Bd * Bd)
                   - (2.0 / Bd) * (double)acc[A_FMU2]
                   + musq * musq
                   - 2.0 * (trG / Bd - musq)
                   + (double)C_N;
        double ortho = (double)acc[A_HFRO] - 2.0 * (double)acc[A_L2SQ] + (double)NCLS_N;
        double loss = 1.0 * nll + 0.2 * kl + 0.2 * cov + 0.1 * ortho
                    + 0.1 * (double)acc[A_L1] + 0.1 * sqrt((double)acc[A_L2SQ]);
        out[0] = (float)loss;
    }
}

extern "C" void kernel_launch(void* const* d_in, const int* in_sizes, int n_in,
                              void* d_out, int out_size, void* d_ws, size_t ws_size,
                              hipStream_t stream) {
    (void)in_sizes; (void)n_in; (void)out_size; (void)ws_size;
    const float* output_lp = (const float*)d_in[0];
    const int*   target    = (const int*)d_in[1];
    const float* W         = (const float*)d_in[2];
    const float* F         = (const float*)d_in[3];

    char*  ws     = (char*)d_ws;
    float* acc    = (float*)(ws + ACC_OFF);
    float* colsum = (float*)(ws + COLSUM_OFF);
    short* Fbt    = (short*)(ws + FBT_OFF);
    short* Wb     = (short*)(ws + WB_OFF);
    float* G      = (float*)(ws + G_OFF);
    float* H      = (float*)(ws + H_OFF);

    // zero accumulators + atomic targets (ws is poisoned 0xAA before every launch)
    hipMemsetAsync(ws, 0, 8192, stream);
    hipMemsetAsync(G, 0, (size_t)C_N * C_N * 4, stream);
    hipMemsetAsync(H, 0, (size_t)1024 * 1024 * 4, stream);

    nll_kernel<<<B_N / 256, 256, 0, stream>>>(output_lp, target, acc);
    wpass_kernel<<<4, 256, 0, stream>>>(W, Wb, acc);
    fpass_kernel<<<dim3(C_N / 256, B_N / 128), 256, 0, stream>>>(F, Fbt, colsum, acc);
    klpass_kernel<<<1024, 256, 0, stream>>>(F, colsum, acc);

    // G = Fbt Fbt^T : Mp=1280, K=16384, T=10, ntri=55, ksplit=8 (chunk 2048) -> 440 blocks
    gram_kernel<<<55 * 8, 256, 0, stream>>>(Fbt, G, C_N, B_N, 10, 55, 2048);
    // H = Wb Wb^T : Mp=1024, K=1280, T=8, ntri=36, ksplit=4 (chunk 320) -> 144 blocks
    gram_kernel<<<36 * 4, 256, 0, stream>>>(Wb, H, 1024, C_N, 8, 36, 320);

    fro_reduce_kernel<<<55, 256, 0, stream>>>(G, C_N, 10, acc + A_GFRO);
    fro_reduce_kernel<<<36, 256, 0, stream>>>(H, 1024, 8, acc + A_HFRO);

    final_kernel<<<1, 256, 0, stream>>>(acc, colsum, (float*)d_out);
}

// Round 4
// 339.949 us; speedup vs baseline: 1.2270x; 1.2270x over previous
//
#include <hip/hip_runtime.h>
#include <stdint.h>
#include <stddef.h>

#define B_N    16384
#define NCLS_N 1000
#define C_N    1280

// workspace layout (bytes). Required ws_size >= ~52.8 MB.
#define ACC_OFF    0ULL
#define COLSUM_OFF 128ULL
#define FBT_OFF    8192ULL                         // bf16 panel [512kc][4kj][1280][8]
#define WB_OFF     41951232ULL                     // bf16 panel [40kc][4kj][1024][8] (rows >=1000 zero)
#define G_OFF      44572672ULL                     // fp32 [1280][1280]
#define H_OFF      51126272ULL                     // fp32 [1024][1024]

enum { A_NLL = 0, A_KL = 1, A_L1 = 2, A_L2SQ = 3, A_SUMSQF = 4, A_FMU2 = 5, A_GFRO = 6, A_HFRO = 7 };

typedef short s16x8 __attribute__((ext_vector_type(8)));
typedef float f32x4 __attribute__((ext_vector_type(4)));

__device__ __forceinline__ unsigned short f2bf(float f) {
    union { float f; unsigned int u; } v; v.f = f;
    unsigned int u = v.u;
    u += 0x7fffu + ((u >> 16) & 1u);   // RNE
    return (unsigned short)(u >> 16);
}

__device__ __forceinline__ float wave_red(float v) {
#pragma unroll
    for (int o = 32; o; o >>= 1) v += __shfl_down(v, o, 64);
    return v;
}

// ---------------- NLL gather ----------------
__global__ __launch_bounds__(256) void nll_kernel(const float* __restrict__ lp,
                                                  const int* __restrict__ tgt,
                                                  float* __restrict__ acc) {
    int b = blockIdx.x * 256 + threadIdx.x;
    int t = tgt[b];
    float v = lp[(size_t)b * NCLS_N + t];
    v = wave_red(v);
    __shared__ float sm[4];
    int wid = threadIdx.x >> 6, lane = threadIdx.x & 63;
    if (lane == 0) sm[wid] = v;
    __syncthreads();
    if (threadIdx.x == 0) atomicAdd(&acc[A_NLL], sm[0] + sm[1] + sm[2] + sm[3]);
}

// ---------------- weights: bf16 panel cast (padded to 1024 rows) + L1 + L2sq ----------------
// grid (4 row-groups, 40 kc). thread = (row m, one 32-k chunk): 128B contiguous read,
// 4 x 16B panel stores (1KB contiguous per wave instr). 160 blocks (round-3's 4-block
// version serialized 5MB through 4 CUs on the critical path).
__global__ __launch_bounds__(256) void wpass_kernel(const float* __restrict__ W,
                                                    short* __restrict__ Wb,
                                                    float* __restrict__ acc) {
    int m = blockIdx.x * 256 + threadIdx.x;     // 0..1023
    int kc = blockIdx.y;                        // 0..39
    bool live = (m < NCLS_N);
    const float4* Wr = (const float4*)(W + (size_t)m * C_N);
    float l1 = 0.f, l2 = 0.f;
#pragma unroll
    for (int kj = 0; kj < 4; kj++) {
        s16x8 pk = { 0, 0, 0, 0, 0, 0, 0, 0 };
        if (live) {
            float4 a = Wr[kc * 8 + kj * 2];
            float4 b = Wr[kc * 8 + kj * 2 + 1];
            l1 += fabsf(a.x) + fabsf(a.y) + fabsf(a.z) + fabsf(a.w)
                + fabsf(b.x) + fabsf(b.y) + fabsf(b.z) + fabsf(b.w);
            l2 += a.x * a.x + a.y * a.y + a.z * a.z + a.w * a.w
                + b.x * b.x + b.y * b.y + b.z * b.z + b.w * b.w;
            pk[0] = (short)f2bf(a.x); pk[1] = (short)f2bf(a.y);
            pk[2] = (short)f2bf(a.z); pk[3] = (short)f2bf(a.w);
            pk[4] = (short)f2bf(b.x); pk[5] = (short)f2bf(b.y);
            pk[6] = (short)f2bf(b.z); pk[7] = (short)f2bf(b.w);
        }
        *(s16x8*)(Wb + ((size_t)(kc * 4 + kj) * 1024 + m) * 8) = pk;
    }
    l1 = wave_red(l1);
    l2 = wave_red(l2);
    __shared__ float sm[4][2];
    int wid = threadIdx.x >> 6, lane = threadIdx.x & 63;
    if (lane == 0) { sm[wid][0] = l1; sm[wid][1] = l2; }
    __syncthreads();
    if (threadIdx.x == 0) {
        atomicAdd(&acc[A_L1],   sm[0][0] + sm[1][0] + sm[2][0] + sm[3][0]);
        atomicAdd(&acc[A_L2SQ], sm[0][1] + sm[1][1] + sm[2][1] + sm[3][1]);
    }
}

// ---------------- features: bf16 panel transpose + column sums + sum of squares ----------------
__global__ __launch_bounds__(256) void fpass_kernel(const float* __restrict__ F,
                                                    short* __restrict__ Fbt,
                                                    float* __restrict__ colsum,
                                                    float* __restrict__ acc) {
    int c = blockIdx.x * 256 + threadIdx.x;     // 0..1279
    int kc0 = blockIdx.y * 4;                   // 4 chunks of 32 k per block
    float cs = 0.f, sq = 0.f;
    for (int ch = 0; ch < 4; ch++) {
        int kc = kc0 + ch;
        int kbase = kc * 32;
#pragma unroll
        for (int kj = 0; kj < 4; kj++) {
            float v[8];
#pragma unroll
            for (int e = 0; e < 8; e++) v[e] = F[(size_t)(kbase + kj * 8 + e) * C_N + c];
            s16x8 pk;
#pragma unroll
            for (int e = 0; e < 8; e++) {
                cs += v[e];
                sq += v[e] * v[e];
                pk[e] = (short)f2bf(v[e]);
            }
            *(s16x8*)(Fbt + ((size_t)(kc * 4 + kj) * C_N + c) * 8) = pk;
        }
    }
    atomicAdd(&colsum[c], cs);
    sq = wave_red(sq);
    __shared__ float sm[4];
    int wid = threadIdx.x >> 6, lane = threadIdx.x & 63;
    if (lane == 0) sm[wid] = sq;
    __syncthreads();
    if (threadIdx.x == 0) atomicAdd(&acc[A_SUMSQF], sm[0] + sm[1] + sm[2] + sm[3]);
}

// ---------------- per-row: KL term + ||F mu||^2 term ----------------
__global__ __launch_bounds__(256) void klpass_kernel(const float* __restrict__ F,
                                                     const float* __restrict__ colsum,
                                                     float* __restrict__ acc) {
    int wid = threadIdx.x >> 6, lane = threadIdx.x & 63;
    int gwave = blockIdx.x * 4 + wid;            // 0..4095
    const float4* M = (const float4*)colsum;

    float kl_acc = 0.f, fmu_acc = 0.f;
    for (int b = gwave; b < B_N; b += 4096) {
        const float4* Fr = (const float4*)(F + (size_t)b * C_N);
        float s = 0.f, tt = 0.f, sf = 0.f, dp = 0.f;
#pragma unroll
        for (int i = 0; i < 5; i++) {
            float4 f = Fr[lane + 64 * i];
            float4 m = M[lane + 64 * i];
            float e0 = __expf(f.x), e1 = __expf(f.y), e2 = __expf(f.z), e3 = __expf(f.w);
            s  += e0 + e1 + e2 + e3;
            tt += e0 * f.x + e1 * f.y + e2 * f.z + e3 * f.w;
            sf += f.x + f.y + f.z + f.w;
            dp += f.x * m.x + f.y * m.y + f.z * m.z + f.w * m.w;
        }
        s = wave_red(s); tt = wave_red(tt); sf = wave_red(sf); dp = wave_red(dp);
        if (lane == 0) {
            kl_acc += (float)C_N * (tt / s) - sf;
            float dot = dp * (1.f / (float)B_N);  // (F mu)_b, mu = colsum/B
            fmu_acc += dot * dot;
        }
    }
    __shared__ float sm[4][2];
    if (lane == 0) { sm[wid][0] = kl_acc; sm[wid][1] = fmu_acc; }
    __syncthreads();
    if (threadIdx.x == 0) {
        atomicAdd(&acc[A_KL],   sm[0][0] + sm[1][0] + sm[2][0] + sm[3][0]);
        atomicAdd(&acc[A_FMU2], sm[0][1] + sm[1][1] + sm[2][1] + sm[3][1]);
    }
}

// ---------------- bf16 Gram: S += X X^T over triangular tiles, K-split, atomic epilogue ----------------
// X: panel layout [kc][kj][Mp][8] bf16 (k = kc*32 + kj*8 + e).
// 128x128 tile per block, 4 waves (2x2 of 64x64), BK=32, 16x16x32 MFMA.
// LDS tile [128 rows][4 slots][8 shorts] with XOR swizzle: slot s at row r holds global
// kj = s ^ (r & 3). Bijective per row; global address SET per wave instr unchanged
// (same 16 rows x 4 kj) so coalescing is identical; frag reads pick slot = quad ^ (row&3).
// This breaks the 64B-row-stride bank aliasing (round-3: 3.6M conflict cycles).
__global__ __launch_bounds__(256) void gram_kernel(const short* __restrict__ X,
                                                   float* __restrict__ S,
                                                   int Mp, int T, int ntri, int chunkK) {
    __shared__ __align__(16) short At[128 * 32];
    __shared__ __align__(16) short Bt[128 * 32];
    int tid = threadIdx.x;
    int tile = blockIdx.x % ntri;
    int kc_blk = blockIdx.x / ntri;
    int bi = 0, rem = tile;
    while (rem >= T - bi) { rem -= T - bi; bi++; }
    int bj = bi + rem;
    int i0 = bi * 128, j0 = bj * 128;
    int k0 = kc_blk * chunkK;
    bool same = (bi == bj);

    int wave = tid >> 6, lane = tid & 63;
    int wm = wave >> 1, wn = wave & 1;
    int quad = lane >> 4, l16 = lane & 15;

    f32x4 acc[4][4];
#pragma unroll
    for (int i = 0; i < 4; i++)
#pragma unroll
        for (int j = 0; j < 4; j++) acc[i][j] = { 0.f, 0.f, 0.f, 0.f };

    for (int kk = 0; kk < chunkK; kk += 32) {
        int kc = (k0 + kk) >> 5;
#pragma unroll
        for (int it = 0; it < 2; it++) {
            int g = it * 256 + tid;
            int row = g >> 2;
            int kj = (g & 3) ^ (row & 3);        // fetch the kj that belongs in this slot
            const short* gp = X + ((size_t)(kc * 4 + kj) * Mp + i0 + row) * 8;
            __builtin_amdgcn_global_load_lds((const __attribute__((address_space(1))) unsigned int*)gp,
                                             (__attribute__((address_space(3))) unsigned int*)(At + g * 8),
                                             16, 0, 0);
        }
        if (!same) {
#pragma unroll
            for (int it = 0; it < 2; it++) {
                int g = it * 256 + tid;
                int row = g >> 2;
                int kj = (g & 3) ^ (row & 3);
                const short* gp = X + ((size_t)(kc * 4 + kj) * Mp + j0 + row) * 8;
                __builtin_amdgcn_global_load_lds((const __attribute__((address_space(1))) unsigned int*)gp,
                                                 (__attribute__((address_space(3))) unsigned int*)(Bt + g * 8),
                                                 16, 0, 0);
            }
        }
        __syncthreads();
        const short* Bsrc = same ? At : Bt;
        s16x8 af[4], bf[4];
#pragma unroll
        for (int f = 0; f < 4; f++) {
            int mrow = wm * 64 + f * 16 + l16;
            af[f] = *(const s16x8*)(At + mrow * 32 + (quad ^ (mrow & 3)) * 8);
            int nrow = wn * 64 + f * 16 + l16;
            bf[f] = *(const s16x8*)(Bsrc + nrow * 32 + (quad ^ (nrow & 3)) * 8);
        }
#pragma unroll
        for (int i = 0; i < 4; i++)
#pragma unroll
            for (int j = 0; j < 4; j++)
                acc[i][j] = __builtin_amdgcn_mfma_f32_16x16x32_bf16(af[i], bf[j], acc[i][j], 0, 0, 0);
        __syncthreads();
    }

#pragma unroll
    for (int i = 0; i < 4; i++)
#pragma unroll
        for (int j = 0; j < 4; j++)
#pragma unroll
            for (int r = 0; r < 4; r++) {
                int grow = i0 + wm * 64 + i * 16 + quad * 4 + r;
                int gcol = j0 + wn * 64 + j * 16 + l16;
                atomicAdd(&S[(size_t)grow * Mp + gcol], acc[i][j][r]);
            }
}

// ---------------- Frobenius^2 over computed triangular tiles (off-diag weighted 2x) ----------------
__global__ __launch_bounds__(256) void fro_reduce_kernel(const float* __restrict__ S,
                                                         int Mp, int T, float* __restrict__ slot) {
    int tile = blockIdx.x;
    int bi = 0, rem = tile;
    while (rem >= T - bi) { rem -= T - bi; bi++; }
    int bj = bi + rem;
    size_t base = (size_t)bi * 128 * Mp + (size_t)bj * 128;
    float sum = 0.f;
    for (int l = threadIdx.x * 4; l < 128 * 128; l += 1024) {
        int row = l >> 7, col = l & 127;
        float4 v = *(const float4*)(S + base + (size_t)row * Mp + col);
        sum += v.x * v.x + v.y * v.y + v.z * v.z + v.w * v.w;
    }
    sum = wave_red(sum);
    __shared__ float sm[4];
    int wid = threadIdx.x >> 6, lane = threadIdx.x & 63;
    if (lane == 0) sm[wid] = sum;
    __syncthreads();
    if (threadIdx.x == 0) {
        float w = (bi == bj) ? 1.f : 2.f;
        atomicAdd(slot, w * (sm[0] + sm[1] + sm[2] + sm[3]));
    }
}

// ---------------- final combine ----------------
__global__ __launch_bounds__(256) void final_kernel(const float* __restrict__ acc,
                                                    const float* __restrict__ colsum,
                                                    float* __restrict__ out) {
    float s = 0.f;
    for (int c = threadIdx.x; c < C_N; c += 256) { float v = colsum[c]; s += v * v; }
    s = wave_red(s);
    __shared__ float sm[4];
    int wid = threadIdx.x >> 6, lane = threadIdx.x & 63;
    if (lane == 0) sm[wid] = s;
    __syncthreads();
    if (threadIdx.x == 0) {
        double musq_raw = (double)(sm[0] + sm[1] + sm[2] + sm[3]);   // sum colsum^2 = B^2 * ||mu||^2
        double Bd = (double)B_N;
        double nll = -((double)acc[A_NLL] / Bd);
        double kl  = (double)acc[A_KL] / Bd;
        double trG = (double)acc[A_SUMSQF];
        double musq = musq_raw / (Bd * Bd);
        double cov = (double)acc[A_GFRO] / (Bd * Bd)
                   - (2.0 / Bd) * (double)acc[A_FMU2]
                   + musq * musq
                   - 2.0 * (trG / Bd - musq)
                   + (double)C_N;
        double ortho = (double)acc[A_HFRO] - 2.0 * (double)acc[A_L2SQ] + (double)NCLS_N;
        double loss = 1.0 * nll + 0.2 * kl + 0.2 * cov + 0.1 * ortho
                    + 0.1 * (double)acc[A_L1] + 0.1 * sqrt((double)acc[A_L2SQ]);
        out[0] = (float)loss;
    }
}

extern "C" void kernel_launch(void* const* d_in, const int* in_sizes, int n_in,
                              void* d_out, int out_size, void* d_ws, size_t ws_size,
                              hipStream_t stream) {
    (void)in_sizes; (void)n_in; (void)out_size; (void)ws_size;
    const float* output_lp = (const float*)d_in[0];
    const int*   target    = (const int*)d_in[1];
    const float* W         = (const float*)d_in[2];
    const float* F         = (const float*)d_in[3];

    char*  ws     = (char*)d_ws;
    float* acc    = (float*)(ws + ACC_OFF);
    float* colsum = (float*)(ws + COLSUM_OFF);
    short* Fbt    = (short*)(ws + FBT_OFF);
    short* Wb     = (short*)(ws + WB_OFF);
    float* G      = (float*)(ws + G_OFF);
    float* H      = (float*)(ws + H_OFF);

    // zero accumulators + atomic targets (ws is poisoned 0xAA before every launch)
    hipMemsetAsync(ws, 0, 8192, stream);
    hipMemsetAsync(G, 0, (size_t)C_N * C_N * 4, stream);
    hipMemsetAsync(H, 0, (size_t)1024 * 1024 * 4, stream);

    nll_kernel<<<B_N / 256, 256, 0, stream>>>(output_lp, target, acc);
    wpass_kernel<<<dim3(4, 40), 256, 0, stream>>>(W, Wb, acc);
    fpass_kernel<<<dim3(C_N / 256, B_N / 128), 256, 0, stream>>>(F, Fbt, colsum, acc);
    klpass_kernel<<<1024, 256, 0, stream>>>(F, colsum, acc);

    // G = Fbt Fbt^T : Mp=1280, T=10, ntri=55, ksplit=16 (chunk 1024) -> 880 blocks (~3.4 waves/SIMD)
    gram_kernel<<<55 * 16, 256, 0, stream>>>(Fbt, G, C_N, 10, 55, 1024);
    // H = Wb Wb^T : Mp=1024, T=8, ntri=36, ksplit=4 (chunk 320) -> 144 blocks
    gram_kernel<<<36 * 4, 256, 0, stream>>>(Wb, H, 1024, 8, 36, 320);

    fro_reduce_kernel<<<55, 256, 0, stream>>>(G, C_N, 10, acc + A_GFRO);
    fro_reduce_kernel<<<36, 256, 0, stream>>>(H, 1024, 8, acc + A_HFRO);

    final_kernel<<<1, 256, 0, stream>>>(acc, colsum, (float*)d_out);
}